// Round 1
// baseline (169.226 us; speedup 1.0000x reference)
//
#include <hip/hip_runtime.h>
#include <hip/hip_bf16.h>

// FermiLayer fused kernel set for MI355X (gfx950).
// Inputs (f32): h1(768,256) h2(768,768,64) W1n(1216,256) b1n(256)
//               W1e(1216,256) b1e(256) W2(4,64,64) b2(4,64)
// Outputs (f32, concat): h1_out(768,256), h2_out(768,768,64)
//
// Pair-type is block structured: row sections {nucl[0,128), up[128,448), dn[448,768)},
// col sections identical. 64-wide tiles never straddle a section boundary.

#define NPART 768
#define NNUCL 128
#define H1OUT_ELEMS (768 * 256)

typedef short short8 __attribute__((ext_vector_type(8)));
typedef float f32x4 __attribute__((ext_vector_type(4)));

__device__ __forceinline__ unsigned short f2bf(float f) {
    unsigned u = __builtin_bit_cast(unsigned, f);
    unsigned r = u + 0x7fffu + ((u >> 16) & 1u);
    return (unsigned short)(r >> 16);
}

// rescaled tanh-approx gelu, already multiplied by GELU_RESCALE
__device__ __forceinline__ float gelu_scaled(float x) {
    float y = 0.7978845608028654f * (x + 0.044715f * x * x * x);
    y = fminf(fmaxf(y, -15.f), 15.f);
    float e = __expf(2.f * y);
    float t = (e - 1.f) / (e + 1.f);
    return 0.5f * x * (1.f + t) * 1.7128586f;
}

// ---------------------------------------------------------------------------
// Kernel 2: h2 update + per-(n, coltile) column partial sums (for h2_mean).
// grid (12, 768), block 256. Each block: one row n, one 64-col tile.
// ---------------------------------------------------------------------------
__global__ __launch_bounds__(256) void k_h2(
    const float* __restrict__ h2, const float* __restrict__ W2,
    const float* __restrict__ b2, float* __restrict__ out2,
    float* __restrict__ part2 /* [768][12][64] */) {
    const int ct = blockIdx.x;  // col tile 0..11
    const int n  = blockIdx.y;  // row 0..767
    const int m0 = ct * 64;

    const int rs = (n < 128) ? 0 : ((n < 448) ? 1 : 2);
    const int cs = (ct < 2) ? 0 : ((ct < 7) ? 1 : 2);
    int p;
    if (rs == 0)      p = (cs == 0) ? 0 : 1;
    else if (rs == 1) p = (cs == 0) ? 1 : ((cs == 1) ? 2 : 3);
    else              p = (cs == 0) ? 1 : ((cs == 1) ? 3 : 2);

    __shared__ float          A32[64][68];   // f32 tile (residual + mean)
    __shared__ unsigned short A16[64][72];   // bf16 tile (MFMA A)
    __shared__ unsigned short BT[64][72];    // bf16 W2[p]^T (MFMA B)
    __shared__ float          red[4][64];

    const int t = threadIdx.x;

    // stage A: h2[n, m0:m0+64, 0:64]
    const float* src = h2 + ((size_t)n * 768 + m0) * 64;
    #pragma unroll
    for (int i = 0; i < 4; ++i) {
        int f4 = i * 256 + t;          // 0..1023 float4s
        int row = f4 >> 4;
        int c4 = (f4 & 15) << 2;
        float4 v = *reinterpret_cast<const float4*>(src + row * 64 + c4);
        *reinterpret_cast<float4*>(&A32[row][c4]) = v;
        ushort4 bv;
        bv.x = f2bf(v.x); bv.y = f2bf(v.y); bv.z = f2bf(v.z); bv.w = f2bf(v.w);
        *reinterpret_cast<ushort4*>(&A16[row][c4]) = bv;
    }
    // stage B^T: BT[e][d] = W2[p][d][e]
    const float* w = W2 + p * 4096;
    #pragma unroll
    for (int i = 0; i < 16; ++i) {
        int idx = i * 256 + t;
        int d = idx >> 6, e = idx & 63;
        BT[e][d] = f2bf(w[idx]);
    }
    __syncthreads();

    // column partial sums (over the 64 m's of this tile), deterministic
    {
        int d = t & 63, mg = t >> 6;
        float s = 0.f;
        #pragma unroll
        for (int m = 0; m < 16; ++m) s += A32[mg * 16 + m][d];
        red[mg][d] = s;
    }
    __syncthreads();
    if (t < 64) {
        float s = red[0][t] + red[1][t] + red[2][t] + red[3][t];
        part2[((size_t)n * 12 + ct) * 64 + t] = s;
    }

    const int lane = t & 63;
    const int wv = t >> 6;
    const int wm = wv >> 1, we = wv & 1;
    const int lr = lane & 15;   // fragment row(A)/col(B,D)
    const int lk = lane >> 4;   // k group

    f32x4 acc[2][2] = {};
    #pragma unroll
    for (int kh = 0; kh < 2; ++kh) {
        short8 aF[2], bF[2];
        int k = kh * 32 + lk * 8;
        #pragma unroll
        for (int fm = 0; fm < 2; ++fm)
            aF[fm] = *reinterpret_cast<const short8*>(&A16[wm * 32 + fm * 16 + lr][k]);
        #pragma unroll
        for (int fe = 0; fe < 2; ++fe)
            bF[fe] = *reinterpret_cast<const short8*>(&BT[we * 32 + fe * 16 + lr][k]);
        #pragma unroll
        for (int fm = 0; fm < 2; ++fm)
            #pragma unroll
            for (int fe = 0; fe < 2; ++fe)
                acc[fm][fe] = __builtin_amdgcn_mfma_f32_16x16x32_bf16(
                    aF[fm], bF[fe], acc[fm][fe], 0, 0, 0);
    }

    // epilogue: bias + gelu + residual
    float* dst = out2 + ((size_t)n * 768 + m0) * 64;
    #pragma unroll
    for (int fm = 0; fm < 2; ++fm) {
        #pragma unroll
        for (int fe = 0; fe < 2; ++fe) {
            int e = we * 32 + fe * 16 + lr;
            float bias = b2[p * 64 + e];
            #pragma unroll
            for (int r = 0; r < 4; ++r) {
                int m = wm * 32 + fm * 16 + lk * 4 + r;
                float x = acc[fm][fe][r] + bias;
                float g = gelu_scaled(x);
                dst[m * 64 + e] = (A32[m][e] + g) * 0.70710678118654752f;
            }
        }
    }
}

// ---------------------------------------------------------------------------
// Kernel 3: per-row-tile partial sums of h1 (for h1_mean). grid 12, block 256.
// ---------------------------------------------------------------------------
__global__ __launch_bounds__(256) void k_h1sum(const float* __restrict__ h1,
                                               float* __restrict__ part1) {
    int tile = blockIdx.x;   // 0..11 (64 rows each)
    int e = threadIdx.x;
    float s = 0.f;
    #pragma unroll 8
    for (int r = 0; r < 64; ++r) s += h1[(size_t)(tile * 64 + r) * 256 + e];
    part1[tile * 256 + e] = s;
}

// ---------------------------------------------------------------------------
// Kernel 4: h1 update. feats(64x1216) @ W(1216x256) per row-tile, MFMA bf16.
// grid (12 row-tiles, 4 col-tiles of 64), block 256.
// ---------------------------------------------------------------------------
__global__ __launch_bounds__(256) void k_h1(
    const float* __restrict__ h1, const float* __restrict__ W1n,
    const float* __restrict__ b1n, const float* __restrict__ W1e,
    const float* __restrict__ b1e, const float* __restrict__ part2,
    const float* __restrict__ part1, float* __restrict__ out1) {
    const int nt = blockIdx.x;   // 0..11
    const int et = blockIdx.y;   // 0..3
    const int n0 = nt * 64, e0 = et * 64;
    const bool nucl = (n0 < NNUCL);
    const float* W  = nucl ? W1n : W1e;
    const float* bb = nucl ? b1n : b1e;
    const bool dnrow = (n0 >= 448);

    __shared__ unsigned short A16[64][72];
    __shared__ unsigned short BT[64][72];

    const int t = threadIdx.x;
    const int lane = t & 63;
    const int wv = t >> 6;
    const int wm = wv >> 1, we = wv & 1;
    const int lr = lane & 15, lk = lane >> 4;

    f32x4 acc[2][2] = {};

    for (int kc = 0; kc < 19; ++kc) {
        const int k0 = kc * 64;
        // ---- stage feats chunk (rows n0..n0+63, k0..k0+63) as bf16 ----
        if (k0 < 256) {
            // region A: h1 itself
            #pragma unroll
            for (int i = 0; i < 4; ++i) {
                int f4 = i * 256 + t;
                int row = f4 >> 4;
                int c4 = (f4 & 15) << 2;
                float4 v = *reinterpret_cast<const float4*>(
                    h1 + (size_t)(n0 + row) * 256 + k0 + c4);
                ushort4 bv;
                bv.x = f2bf(v.x); bv.y = f2bf(v.y); bv.z = f2bf(v.z); bv.w = f2bf(v.w);
                *reinterpret_cast<ushort4*>(&A16[row][c4]) = bv;
            }
        } else if (k0 < 448) {
            // region B: h2_mean (row-dependent, spin-swapped for dn rows)
            #pragma unroll
            for (int i = 0; i < 16; ++i) {
                int idx = i * 256 + t;
                int row = idx >> 6, kk = idx & 63;
                int j = k0 + kk - 256;               // 0..191
                int sec = j >> 6, d = j & 63;
                int s2 = (dnrow && sec >= 1) ? (3 - sec) : sec;
                const float* pr = part2 + (size_t)(n0 + row) * 12 * 64;
                float s;
                if (s2 == 0) {
                    s = (pr[0 * 64 + d] + pr[1 * 64 + d]) * (1.f / 128.f);
                } else if (s2 == 1) {
                    s = 0.f;
                    #pragma unroll
                    for (int q = 2; q < 7; ++q) s += pr[q * 64 + d];
                    s *= (1.f / 320.f);
                } else {
                    s = 0.f;
                    #pragma unroll
                    for (int q = 7; q < 12; ++q) s += pr[q * 64 + d];
                    s *= (1.f / 320.f);
                }
                A16[row][kk] = f2bf(s);
            }
        } else {
            // region C: h1_mean (identical for all rows of this block)
            int kk = t & 63, rg = t >> 6;
            int j = k0 + kk - 448;                   // 0..767
            int sec = j >> 8, e2 = j & 255;
            int s2 = (dnrow && sec >= 1) ? (3 - sec) : sec;
            float s;
            if (s2 == 0) {
                s = (part1[0 * 256 + e2] + part1[1 * 256 + e2]) * (1.f / 128.f);
            } else if (s2 == 1) {
                s = 0.f;
                #pragma unroll
                for (int q = 2; q < 7; ++q) s += part1[q * 256 + e2];
                s *= (1.f / 320.f);
            } else {
                s = 0.f;
                #pragma unroll
                for (int q = 7; q < 12; ++q) s += part1[q * 256 + e2];
                s *= (1.f / 320.f);
            }
            unsigned short bv = f2bf(s);
            #pragma unroll
            for (int r = 0; r < 16; ++r) A16[rg * 16 + r][kk] = bv;
        }
        // ---- stage W chunk transposed: BT[e_l][kk] = W[k0+kk][e0+e_l] ----
        #pragma unroll
        for (int i = 0; i < 16; ++i) {
            int idx = i * 256 + t;
            int kk = idx >> 6, el = idx & 63;
            BT[el][kk] = f2bf(W[(size_t)(k0 + kk) * 256 + e0 + el]);
        }
        __syncthreads();

        #pragma unroll
        for (int kh = 0; kh < 2; ++kh) {
            short8 aF[2], bF[2];
            int k = kh * 32 + lk * 8;
            #pragma unroll
            for (int fm = 0; fm < 2; ++fm)
                aF[fm] = *reinterpret_cast<const short8*>(&A16[wm * 32 + fm * 16 + lr][k]);
            #pragma unroll
            for (int fe = 0; fe < 2; ++fe)
                bF[fe] = *reinterpret_cast<const short8*>(&BT[we * 32 + fe * 16 + lr][k]);
            #pragma unroll
            for (int fm = 0; fm < 2; ++fm)
                #pragma unroll
                for (int fe = 0; fe < 2; ++fe)
                    acc[fm][fe] = __builtin_amdgcn_mfma_f32_16x16x32_bf16(
                        aF[fm], bF[fe], acc[fm][fe], 0, 0, 0);
        }
        __syncthreads();
    }

    // epilogue
    #pragma unroll
    for (int fm = 0; fm < 2; ++fm) {
        #pragma unroll
        for (int fe = 0; fe < 2; ++fe) {
            int e = e0 + we * 32 + fe * 16 + lr;
            float bias = bb[e];
            #pragma unroll
            for (int r = 0; r < 4; ++r) {
                int n = n0 + wm * 32 + fm * 16 + lk * 4 + r;
                float x = acc[fm][fe][r] + bias;
                float g = gelu_scaled(x);
                out1[(size_t)n * 256 + e] =
                    (h1[(size_t)n * 256 + e] + g) * 0.70710678118654752f;
            }
        }
    }
}

// ---------------------------------------------------------------------------
extern "C" void kernel_launch(void* const* d_in, const int* in_sizes, int n_in,
                              void* d_out, int out_size, void* d_ws, size_t ws_size,
                              hipStream_t stream) {
    const float* h1  = (const float*)d_in[0];
    const float* h2  = (const float*)d_in[1];
    const float* W1n = (const float*)d_in[2];
    const float* b1n = (const float*)d_in[3];
    const float* W1e = (const float*)d_in[4];
    const float* b1e = (const float*)d_in[5];
    const float* W2  = (const float*)d_in[6];
    const float* b2  = (const float*)d_in[7];

    float* out1 = (float*)d_out;             // h1_out: 768*256
    float* out2 = out1 + H1OUT_ELEMS;        // h2_out: 768*768*64

    float* part2 = (float*)d_ws;             // 768*12*64 f32 (h2 col partials)
    float* part1 = part2 + 768 * 12 * 64;    // 12*256   f32 (h1 row partials)

    k_h2<<<dim3(12, 768), 256, 0, stream>>>(h2, W2, b2, out2, part2);
    k_h1sum<<<12, 256, 0, stream>>>(h1, part1);
    k_h1<<<dim3(12, 4), 256, 0, stream>>>(h1, W1n, b1n, W1e, b1e,
                                          part2, part1, out1);
}

// Round 2
// 86.547 us; speedup vs baseline: 1.9553x; 1.9553x over previous
//
#include <hip/hip_runtime.h>
#include <hip/hip_bf16.h>

// FermiLayer fused kernel set for MI355X (gfx950).
// Inputs (f32): h1(768,256) h2(768,768,64) W1n(1216,256) b1n(256)
//               W1e(1216,256) b1e(256) W2(4,64,64) b2(4,64)
// Outputs (f32, concat): h1_out(768,256), h2_out(768,768,64)

#define NPART 768
#define NNUCL 128
#define H1OUT_ELEMS (768 * 256)

typedef short short8 __attribute__((ext_vector_type(8)));
typedef float f32x4 __attribute__((ext_vector_type(4)));

__device__ __forceinline__ unsigned short f2bf(float f) {
    unsigned u = __builtin_bit_cast(unsigned, f);
    unsigned r = u + 0x7fffu + ((u >> 16) & 1u);
    return (unsigned short)(r >> 16);
}

// rescaled tanh-approx gelu, already multiplied by GELU_RESCALE
__device__ __forceinline__ float gelu_scaled(float x) {
    float y = 0.7978845608028654f * (x + 0.044715f * x * x * x);
    y = fminf(fmaxf(y, -15.f), 15.f);
    float e = __expf(2.f * y);
    float t = (e - 1.f) / (e + 1.f);
    return 0.5f * x * (1.f + t) * 1.7128586f;
}

// ---------------------------------------------------------------------------
// Kernel: h2 update + per-(n, coltile) column partial sums (for h2_mean).
// grid (12, 768), block 256. Each block: one row n, one 64-col tile.
// ---------------------------------------------------------------------------
__global__ __launch_bounds__(256) void k_h2(
    const float* __restrict__ h2, const float* __restrict__ W2,
    const float* __restrict__ b2, float* __restrict__ out2,
    float* __restrict__ part2 /* [768][12][64] */) {
    const int ct = blockIdx.x;  // col tile 0..11
    const int n  = blockIdx.y;  // row 0..767
    const int m0 = ct * 64;

    const int rs = (n < 128) ? 0 : ((n < 448) ? 1 : 2);
    const int cs = (ct < 2) ? 0 : ((ct < 7) ? 1 : 2);
    int p;
    if (rs == 0)      p = (cs == 0) ? 0 : 1;
    else if (rs == 1) p = (cs == 0) ? 1 : ((cs == 1) ? 2 : 3);
    else              p = (cs == 0) ? 1 : ((cs == 1) ? 3 : 2);

    __shared__ float          A32[64][68];   // f32 tile (residual + mean)
    __shared__ unsigned short A16[64][72];   // bf16 tile (MFMA A)
    __shared__ unsigned short BT[64][72];    // bf16 W2[p]^T (MFMA B)
    __shared__ float          red[4][64];

    const int t = threadIdx.x;

    // stage A: h2[n, m0:m0+64, 0:64]
    const float* src = h2 + ((size_t)n * 768 + m0) * 64;
    #pragma unroll
    for (int i = 0; i < 4; ++i) {
        int f4 = i * 256 + t;          // 0..1023 float4s
        int row = f4 >> 4;
        int c4 = (f4 & 15) << 2;
        float4 v = *reinterpret_cast<const float4*>(src + row * 64 + c4);
        *reinterpret_cast<float4*>(&A32[row][c4]) = v;
        ushort4 bv;
        bv.x = f2bf(v.x); bv.y = f2bf(v.y); bv.z = f2bf(v.z); bv.w = f2bf(v.w);
        *reinterpret_cast<ushort4*>(&A16[row][c4]) = bv;
    }
    // stage B^T: BT[e][d] = W2[p][d][e]
    const float* w = W2 + p * 4096;
    #pragma unroll
    for (int i = 0; i < 16; ++i) {
        int idx = i * 256 + t;
        int d = idx >> 6, e = idx & 63;
        BT[e][d] = f2bf(w[idx]);
    }
    __syncthreads();

    // column partial sums (over the 64 m's of this tile), deterministic
    {
        int d = t & 63, mg = t >> 6;
        float s = 0.f;
        #pragma unroll
        for (int m = 0; m < 16; ++m) s += A32[mg * 16 + m][d];
        red[mg][d] = s;
    }
    __syncthreads();
    if (t < 64) {
        float s = red[0][t] + red[1][t] + red[2][t] + red[3][t];
        part2[((size_t)n * 12 + ct) * 64 + t] = s;
    }

    const int lane = t & 63;
    const int wv = t >> 6;
    const int wm = wv >> 1, we = wv & 1;
    const int lr = lane & 15;   // fragment row(A)/col(B,D)
    const int lk = lane >> 4;   // k group

    f32x4 acc[2][2] = {};
    #pragma unroll
    for (int kh = 0; kh < 2; ++kh) {
        short8 aF[2], bF[2];
        int k = kh * 32 + lk * 8;
        #pragma unroll
        for (int fm = 0; fm < 2; ++fm)
            aF[fm] = *reinterpret_cast<const short8*>(&A16[wm * 32 + fm * 16 + lr][k]);
        #pragma unroll
        for (int fe = 0; fe < 2; ++fe)
            bF[fe] = *reinterpret_cast<const short8*>(&BT[we * 32 + fe * 16 + lr][k]);
        #pragma unroll
        for (int fm = 0; fm < 2; ++fm)
            #pragma unroll
            for (int fe = 0; fe < 2; ++fe)
                acc[fm][fe] = __builtin_amdgcn_mfma_f32_16x16x32_bf16(
                    aF[fm], bF[fe], acc[fm][fe], 0, 0, 0);
    }

    // epilogue: bias + gelu + residual
    float* dst = out2 + ((size_t)n * 768 + m0) * 64;
    #pragma unroll
    for (int fm = 0; fm < 2; ++fm) {
        #pragma unroll
        for (int fe = 0; fe < 2; ++fe) {
            int e = we * 32 + fe * 16 + lr;
            float bias = b2[p * 64 + e];
            #pragma unroll
            for (int r = 0; r < 4; ++r) {
                int m = wm * 32 + fm * 16 + lk * 4 + r;
                float x = acc[fm][fe][r] + bias;
                float g = gelu_scaled(x);
                dst[m * 64 + e] = (A32[m][e] + g) * 0.70710678118654752f;
            }
        }
    }
}

// ---------------------------------------------------------------------------
// Kernel: per-row-tile partial sums of h1 (for h1_mean). grid 12, block 256.
// ---------------------------------------------------------------------------
__global__ __launch_bounds__(256) void k_h1sum(const float* __restrict__ h1,
                                               float* __restrict__ part1) {
    int tile = blockIdx.x;   // 0..11 (64 rows each)
    int e = threadIdx.x;
    float s = 0.f;
    #pragma unroll 8
    for (int r = 0; r < 64; ++r) s += h1[(size_t)(tile * 64 + r) * 256 + e];
    part1[tile * 256 + e] = s;
}

// ---------------------------------------------------------------------------
// Kernel: transpose-convert W1n/W1e (1216x256 f32) -> WT[2][256][1216] bf16.
// grid (19, 4, 2), block 256. LDS-tiled 64x64 transpose.
// ---------------------------------------------------------------------------
__global__ __launch_bounds__(256) void k_wconv(
    const float* __restrict__ W1n, const float* __restrict__ W1e,
    unsigned short* __restrict__ WT) {
    const int k0 = blockIdx.x * 64;
    const int e0 = blockIdx.y * 64;
    const int mtx = blockIdx.z;
    const float* W = mtx ? W1e : W1n;
    __shared__ float tile[64][65];
    const int t = threadIdx.x;
    #pragma unroll
    for (int i = 0; i < 16; ++i) {
        int idx = i * 256 + t;
        int kr = idx >> 6, ec = idx & 63;
        tile[kr][ec] = W[(size_t)(k0 + kr) * 256 + e0 + ec];
    }
    __syncthreads();
    #pragma unroll
    for (int i = 0; i < 16; ++i) {
        int idx = i * 256 + t;
        int er = idx >> 6, kc = idx & 63;
        WT[((size_t)mtx * 256 + e0 + er) * 1216 + k0 + kc] = f2bf(tile[kc][er]);
    }
}

// ---------------------------------------------------------------------------
// Kernel: materialize feats (768 x 1216) in bf16.
// feats[n] = [ h1[n] (256) | h2_mean flat (192) | h1_mean flat (768) ]
// grid 768, block 256.
// ---------------------------------------------------------------------------
__global__ __launch_bounds__(256) void k_feats(
    const float* __restrict__ h1, const float* __restrict__ part2,
    const float* __restrict__ part1, unsigned short* __restrict__ feats) {
    const int n = blockIdx.x;
    const bool dnrow = (n >= 448);
    const int t = threadIdx.x;
    unsigned short* fr = feats + (size_t)n * 1216;

    // h1 slice
    fr[t] = f2bf(h1[(size_t)n * 256 + t]);

    // h2_mean slice (192), spin-swapped for dn rows
    if (t < 192) {
        int sec = t >> 6, d = t & 63;
        int s2 = (dnrow && sec >= 1) ? (3 - sec) : sec;
        const float* pr = part2 + (size_t)n * 768;
        float s;
        if (s2 == 0) {
            s = (pr[d] + pr[64 + d]) * (1.f / 128.f);
        } else if (s2 == 1) {
            s = 0.f;
            #pragma unroll
            for (int q = 2; q < 7; ++q) s += pr[q * 64 + d];
            s *= (1.f / 320.f);
        } else {
            s = 0.f;
            #pragma unroll
            for (int q = 7; q < 12; ++q) s += pr[q * 64 + d];
            s *= (1.f / 320.f);
        }
        fr[256 + t] = f2bf(s);
    }

    // h1_mean slice (768), spin-swapped for dn rows
    #pragma unroll
    for (int i = 0; i < 3; ++i) {
        int j = i * 256 + t;
        int sec = j >> 8, e2 = j & 255;
        int s2 = (dnrow && sec >= 1) ? (3 - sec) : sec;
        float s;
        if (s2 == 0) {
            s = (part1[e2] + part1[256 + e2]) * (1.f / 128.f);
        } else if (s2 == 1) {
            s = 0.f;
            #pragma unroll
            for (int q = 2; q < 7; ++q) s += part1[q * 256 + e2];
            s *= (1.f / 320.f);
        } else {
            s = 0.f;
            #pragma unroll
            for (int q = 7; q < 12; ++q) s += part1[q * 256 + e2];
            s *= (1.f / 320.f);
        }
        fr[448 + j] = f2bf(s);
    }
}

// ---------------------------------------------------------------------------
// Kernel: h1 GEMM. One 16x16 MFMA tile per wave, K=1216, operands bf16 in L2.
// grid (48 M-tiles, 4), block 256 (4 waves -> 4 consecutive N-tiles).
// ---------------------------------------------------------------------------
__global__ __launch_bounds__(256) void k_h1g(
    const unsigned short* __restrict__ feats, const unsigned short* __restrict__ WT,
    const float* __restrict__ b1n, const float* __restrict__ b1e,
    const float* __restrict__ h1, float* __restrict__ out1) {
    const int m0 = blockIdx.x * 16;
    const int wv = threadIdx.x >> 6;
    const int e0 = (blockIdx.y * 4 + wv) * 16;
    const int lane = threadIdx.x & 63;
    const int lr = lane & 15, lk = lane >> 4;
    const bool nucl = (m0 < NNUCL);
    const unsigned short* BT = WT + (nucl ? 0 : (size_t)256 * 1216);
    const float* bb = nucl ? b1n : b1e;

    const unsigned short* arow = feats + (size_t)(m0 + lr) * 1216 + lk * 8;
    const unsigned short* brow = BT + (size_t)(e0 + lr) * 1216 + lk * 8;

    f32x4 acc = {};
    #pragma unroll 2
    for (int k = 0; k < 1216; k += 32) {
        short8 aF = *reinterpret_cast<const short8*>(arow + k);
        short8 bF = *reinterpret_cast<const short8*>(brow + k);
        acc = __builtin_amdgcn_mfma_f32_16x16x32_bf16(aF, bF, acc, 0, 0, 0);
    }

    const int e = e0 + lr;
    const float bias = bb[e];
    #pragma unroll
    for (int r = 0; r < 4; ++r) {
        int m = m0 + lk * 4 + r;
        float x = acc[r] + bias;
        float g = gelu_scaled(x);
        out1[(size_t)m * 256 + e] =
            (h1[(size_t)m * 256 + e] + g) * 0.70710678118654752f;
    }
}

// ---------------------------------------------------------------------------
extern "C" void kernel_launch(void* const* d_in, const int* in_sizes, int n_in,
                              void* d_out, int out_size, void* d_ws, size_t ws_size,
                              hipStream_t stream) {
    const float* h1  = (const float*)d_in[0];
    const float* h2  = (const float*)d_in[1];
    const float* W1n = (const float*)d_in[2];
    const float* b1n = (const float*)d_in[3];
    const float* W1e = (const float*)d_in[4];
    const float* b1e = (const float*)d_in[5];
    const float* W2  = (const float*)d_in[6];
    const float* b2  = (const float*)d_in[7];

    float* out1 = (float*)d_out;             // h1_out: 768*256
    float* out2 = out1 + H1OUT_ELEMS;        // h2_out: 768*768*64

    float* part2 = (float*)d_ws;                       // 768*12*64 f32
    float* part1 = part2 + 768 * 12 * 64;              // 12*256 f32
    unsigned short* feats = (unsigned short*)(part1 + 12 * 256);  // 768*1216 bf16
    unsigned short* WT    = feats + (size_t)768 * 1216;           // 2*256*1216 bf16

    k_h1sum<<<12, 256, 0, stream>>>(h1, part1);
    k_wconv<<<dim3(19, 4, 2), 256, 0, stream>>>(W1n, W1e, WT);
    k_h2<<<dim3(12, 768), 256, 0, stream>>>(h2, W2, b2, out2, part2);
    k_feats<<<768, 256, 0, stream>>>(h1, part2, part1, feats);
    k_h1g<<<dim3(48, 4), 256, 0, stream>>>(feats, WT, b1n, b1e, h1, out1);
}

// Round 3
// 86.283 us; speedup vs baseline: 1.9613x; 1.0031x over previous
//
#include <hip/hip_runtime.h>

// FermiLayer fused kernel set for MI355X (gfx950).
// Inputs (f32): h1(768,256) h2(768,768,64) W1n(1216,256) b1n(256)
//               W1e(1216,256) b1e(256) W2(4,64,64) b2(4,64)
// Outputs (f32, concat): h1_out(768,256), h2_out(768,768,64)

#define H1OUT_ELEMS (768 * 256)

typedef short short8 __attribute__((ext_vector_type(8)));
typedef float f32x4 __attribute__((ext_vector_type(4)));

__device__ __forceinline__ unsigned short f2bf(float f) {
    unsigned u = __builtin_bit_cast(unsigned, f);
    unsigned r = u + 0x7fffu + ((u >> 16) & 1u);
    return (unsigned short)(r >> 16);
}

// out = (hv + gelu_rescaled(x)) / sqrt(2), tanh-approx gelu.
// gelu(x) = x * sigmoid(2y), y = 0.79788456(x + 0.044715 x^3)
// exp(-2y) = exp2(x * (-0.1029432196 x^2 - 2.3025850930))
__device__ __forceinline__ float gelu_res(float x, float hv) {
    float x2 = x * x;
    float z = x * fmaf(-0.1029432196f, x2, -2.3025850930f);
    float e = __builtin_amdgcn_exp2f(z);
    float r = __builtin_amdgcn_rcpf(1.f + e);
    return fmaf(x * r, 1.2111740f, hv * 0.70710678f);
}

// ---------------------------------------------------------------------------
// Fused kernel 1: blocks [0,12): h1 per-tile column sums -> part1
//                 blocks [12,164): W1n/W1e transpose-convert -> WT bf16
//                 blocks [164,164+9216): h2 update + column partial sums
// ---------------------------------------------------------------------------
__global__ __launch_bounds__(256) void k_h2pre(
    const float* __restrict__ h2, const float* __restrict__ W2,
    const float* __restrict__ b2, const float* __restrict__ h1,
    const float* __restrict__ W1n, const float* __restrict__ W1e,
    float* __restrict__ out2, float* __restrict__ part2,
    float* __restrict__ part1, unsigned short* __restrict__ WT) {
    __shared__ union SM {
        struct {
            unsigned short A16[64][72];
            unsigned short BT[64][72];
            float          red[16][68];
        } g;
        float tile[64][65];
    } sm;

    int b = blockIdx.x;
    const int t = threadIdx.x;

    if (b < 12) {  // ---- h1 per-64-row-tile column sums ----
        float s = 0.f;
        #pragma unroll 8
        for (int r = 0; r < 64; ++r) s += h1[(size_t)(b * 64 + r) * 256 + t];
        part1[b * 256 + t] = s;
        return;
    }
    if (b < 164) {  // ---- W transpose-convert ----
        int idx = b - 12;            // 0..151
        int mtx = idx / 76;
        int r2  = idx % 76;
        int k0 = (r2 / 4) * 64, e0 = (r2 % 4) * 64;
        const float* W = mtx ? W1e : W1n;
        #pragma unroll
        for (int i = 0; i < 16; ++i) {
            int j = i * 256 + t;
            int kr = j >> 6, ec = j & 63;
            sm.tile[kr][ec] = W[(size_t)(k0 + kr) * 256 + e0 + ec];
        }
        __syncthreads();
        #pragma unroll
        for (int i = 0; i < 16; ++i) {
            int j = i * 256 + t;
            int er = j >> 6, kc = j & 63;
            WT[((size_t)mtx * 256 + e0 + er) * 1216 + k0 + kc] = f2bf(sm.tile[kc][er]);
        }
        return;
    }

    // ---- h2 update ----
    b -= 164;
    const int ct = b % 12;
    const int n  = b / 12;
    const int m0 = ct * 64;

    const int rs = (n < 128) ? 0 : ((n < 448) ? 1 : 2);
    const int cs = (ct < 2) ? 0 : ((ct < 7) ? 1 : 2);
    int p;
    if (rs == 0)      p = (cs == 0) ? 0 : 1;
    else if (rs == 1) p = (cs == 0) ? 1 : ((cs == 1) ? 2 : 3);
    else              p = (cs == 0) ? 1 : ((cs == 1) ? 3 : 2);

    const float* src = h2 + ((size_t)n * 768 + m0) * 64;
    const int row0 = t >> 4, c4 = (t & 15) << 2;

    // stage 64x64 tile: 4 float4 per thread (rows row0+16i, cols c4..c4+3)
    float4 v0 = *reinterpret_cast<const float4*>(src + (row0 +  0) * 64 + c4);
    float4 v1 = *reinterpret_cast<const float4*>(src + (row0 + 16) * 64 + c4);
    float4 v2 = *reinterpret_cast<const float4*>(src + (row0 + 32) * 64 + c4);
    float4 v3 = *reinterpret_cast<const float4*>(src + (row0 + 48) * 64 + c4);

    {
        ushort4 bv;
        bv.x = f2bf(v0.x); bv.y = f2bf(v0.y); bv.z = f2bf(v0.z); bv.w = f2bf(v0.w);
        *reinterpret_cast<ushort4*>(&sm.g.A16[row0][c4]) = bv;
        bv.x = f2bf(v1.x); bv.y = f2bf(v1.y); bv.z = f2bf(v1.z); bv.w = f2bf(v1.w);
        *reinterpret_cast<ushort4*>(&sm.g.A16[row0 + 16][c4]) = bv;
        bv.x = f2bf(v2.x); bv.y = f2bf(v2.y); bv.z = f2bf(v2.z); bv.w = f2bf(v2.w);
        *reinterpret_cast<ushort4*>(&sm.g.A16[row0 + 32][c4]) = bv;
        bv.x = f2bf(v3.x); bv.y = f2bf(v3.y); bv.z = f2bf(v3.z); bv.w = f2bf(v3.w);
        *reinterpret_cast<ushort4*>(&sm.g.A16[row0 + 48][c4]) = bv;
    }
    {   // column partial sums from registers
        float4 cs4;
        cs4.x = v0.x + v1.x + v2.x + v3.x;
        cs4.y = v0.y + v1.y + v2.y + v3.y;
        cs4.z = v0.z + v1.z + v2.z + v3.z;
        cs4.w = v0.w + v1.w + v2.w + v3.w;
        *reinterpret_cast<float4*>(&sm.g.red[row0][c4]) = cs4;
    }
    // stage B^T: BT[e][d] = W2[p][d][e]
    const float* w = W2 + p * 4096;
    #pragma unroll
    for (int i = 0; i < 16; ++i) {
        int idx = i * 256 + t;
        int d = idx >> 6, e = idx & 63;
        sm.g.BT[e][d] = f2bf(w[idx]);
    }
    __syncthreads();

    const int lane = t & 63;
    const int wv = t >> 6;

    if (wv == 0) {  // finalize column sums (wave-uniform)
        float s = 0.f;
        #pragma unroll
        for (int r = 0; r < 16; ++r) s += sm.g.red[r][lane];
        part2[((size_t)n * 12 + ct) * 64 + lane] = s;
    }

    const int wm = wv >> 1, we = wv & 1;
    const int lr = lane & 15;
    const int lk = lane >> 4;

    f32x4 acc[2][2] = {};
    #pragma unroll
    for (int kh = 0; kh < 2; ++kh) {
        short8 aF[2], bF[2];
        int k = kh * 32 + lk * 8;
        #pragma unroll
        for (int fm = 0; fm < 2; ++fm)
            aF[fm] = *reinterpret_cast<const short8*>(&sm.g.A16[wm * 32 + fm * 16 + lr][k]);
        #pragma unroll
        for (int fe = 0; fe < 2; ++fe)
            bF[fe] = *reinterpret_cast<const short8*>(&sm.g.BT[we * 32 + fe * 16 + lr][k]);
        #pragma unroll
        for (int fm = 0; fm < 2; ++fm)
            #pragma unroll
            for (int fe = 0; fe < 2; ++fe)
                acc[fm][fe] = __builtin_amdgcn_mfma_f32_16x16x32_bf16(
                    aF[fm], bF[fe], acc[fm][fe], 0, 0, 0);
    }

    // epilogue: bias + gelu + residual (h2 value re-read, L2-resident)
    float* dst = out2 + ((size_t)n * 768 + m0) * 64;
    #pragma unroll
    for (int fm = 0; fm < 2; ++fm) {
        #pragma unroll
        for (int fe = 0; fe < 2; ++fe) {
            int e = we * 32 + fe * 16 + lr;
            float bias = b2[p * 64 + e];
            #pragma unroll
            for (int r = 0; r < 4; ++r) {
                int m = wm * 32 + fm * 16 + lk * 4 + r;
                float hv = src[m * 64 + e];
                float o = gelu_res(acc[fm][fe][r] + bias, hv);
                __builtin_nontemporal_store(o, dst + m * 64 + e);
            }
        }
    }
}

// ---------------------------------------------------------------------------
// Fused kernel 2: build feats rows (16) in LDS, then GEMM vs WT + epilogue.
// grid (48, 2), block 256 (4 waves; each wave 32 output cols).
// ---------------------------------------------------------------------------
__global__ __launch_bounds__(256) void k_h1f(
    const float* __restrict__ h1, const unsigned short* __restrict__ WT,
    const float* __restrict__ part2, const float* __restrict__ part1,
    const float* __restrict__ b1n, const float* __restrict__ b1e,
    float* __restrict__ out1) {
    __shared__ unsigned short FL[16][1224];   // 16 feats rows, stride 1224 (16B-aligned, spread)

    const int n0 = blockIdx.x * 16;
    const int half = blockIdx.y;
    const int t = threadIdx.x;
    const bool dn = (n0 >= 448);
    const bool nucl = (n0 < 128);

    // phase 1: h1 slice (cols 0..255)
    #pragma unroll
    for (int i = 0; i < 16; ++i) {
        int idx = i * 256 + t;
        int r = idx >> 8, c = idx & 255;
        FL[r][c] = f2bf(h1[(size_t)(n0 + r) * 256 + c]);
    }
    // phase 2: h2_mean (cols 256..447), 16 rows x 192
    #pragma unroll
    for (int i = 0; i < 12; ++i) {
        int idx = i * 256 + t;
        int r = idx / 192, c = idx % 192;
        int sec = c >> 6, d = c & 63;
        int s2 = (dn && sec >= 1) ? (3 - sec) : sec;
        const float* pr = part2 + (size_t)(n0 + r) * 768;
        float s;
        if (s2 == 0) {
            s = (pr[d] + pr[64 + d]) * (1.f / 128.f);
        } else {
            int q0 = (s2 == 1) ? 2 : 7;
            s = 0.f;
            #pragma unroll
            for (int q = 0; q < 5; ++q) s += pr[(q0 + q) * 64 + d];
            s *= (1.f / 320.f);
        }
        FL[r][256 + c] = f2bf(s);
    }
    // phase 3: h1_mean (cols 448..1215), shared across the 16 rows
    #pragma unroll
    for (int i = 0; i < 3; ++i) {
        int j = i * 256 + t;
        int sec = j >> 8, e2 = j & 255;
        int s2 = (dn && sec >= 1) ? (3 - sec) : sec;
        float s;
        if (s2 == 0) {
            s = (part1[e2] + part1[256 + e2]) * (1.f / 128.f);
        } else {
            int q0 = (s2 == 1) ? 2 : 7;
            s = 0.f;
            #pragma unroll
            for (int q = 0; q < 5; ++q) s += part1[(q0 + q) * 256 + e2];
            s *= (1.f / 320.f);
        }
        unsigned short bv = f2bf(s);
        #pragma unroll
        for (int r = 0; r < 16; ++r) FL[r][448 + j] = bv;
    }
    __syncthreads();

    const int w = t >> 6, lane = t & 63;
    const int lr = lane & 15, lk = lane >> 4;
    const int e0 = half * 128 + w * 32;
    const unsigned short* BT = WT + (nucl ? 0 : (size_t)256 * 1216);
    const unsigned short* br0 = BT + (size_t)(e0 + lr) * 1216 + lk * 8;
    const unsigned short* br1 = br0 + (size_t)16 * 1216;
    const unsigned short* ar = &FL[lr][lk * 8];

    f32x4 acc0 = {}, acc1 = {};
    #pragma unroll 2
    for (int k = 0; k < 1216; k += 32) {
        short8 aF = *reinterpret_cast<const short8*>(ar + k);
        short8 b0 = *reinterpret_cast<const short8*>(br0 + k);
        short8 b1 = *reinterpret_cast<const short8*>(br1 + k);
        acc0 = __builtin_amdgcn_mfma_f32_16x16x32_bf16(aF, b0, acc0, 0, 0, 0);
        acc1 = __builtin_amdgcn_mfma_f32_16x16x32_bf16(aF, b1, acc1, 0, 0, 0);
    }

    const float* bb = nucl ? b1n : b1e;
    #pragma unroll
    for (int j = 0; j < 2; ++j) {
        const f32x4 a = j ? acc1 : acc0;
        int e = e0 + j * 16 + lr;
        float bias = bb[e];
        #pragma unroll
        for (int r = 0; r < 4; ++r) {
            int m = n0 + lk * 4 + r;
            float hv = h1[(size_t)m * 256 + e];
            out1[(size_t)m * 256 + e] = gelu_res(a[r] + bias, hv);
        }
    }
}

// ---------------------------------------------------------------------------
extern "C" void kernel_launch(void* const* d_in, const int* in_sizes, int n_in,
                              void* d_out, int out_size, void* d_ws, size_t ws_size,
                              hipStream_t stream) {
    const float* h1  = (const float*)d_in[0];
    const float* h2  = (const float*)d_in[1];
    const float* W1n = (const float*)d_in[2];
    const float* b1n = (const float*)d_in[3];
    const float* W1e = (const float*)d_in[4];
    const float* b1e = (const float*)d_in[5];
    const float* W2  = (const float*)d_in[6];
    const float* b2  = (const float*)d_in[7];

    float* out1 = (float*)d_out;             // h1_out: 768*256
    float* out2 = out1 + H1OUT_ELEMS;        // h2_out: 768*768*64

    float* part2 = (float*)d_ws;                                  // 768*12*64 f32
    float* part1 = part2 + 768 * 12 * 64;                         // 12*256 f32
    unsigned short* WT = (unsigned short*)(part1 + 12 * 256);     // 2*256*1216 bf16

    k_h2pre<<<dim3(164 + 12 * 768), 256, 0, stream>>>(
        h2, W2, b2, h1, W1n, W1e, out2, part2, part1, WT);
    k_h1f<<<dim3(48, 2), 256, 0, stream>>>(h1, WT, part2, part1, b1n, b1e, out1);
}

// Round 4
// 82.299 us; speedup vs baseline: 2.0562x; 1.0484x over previous
//
#include <hip/hip_runtime.h>

// FermiLayer fused kernel set for MI355X (gfx950).
// Inputs (f32): h1(768,256) h2(768,768,64) W1n(1216,256) b1n(256)
//               W1e(1216,256) b1e(256) W2(4,64,64) b2(4,64)
// Outputs (f32, concat): h1_out(768,256), h2_out(768,768,64)

#define H1OUT_ELEMS (768 * 256)

typedef short short8 __attribute__((ext_vector_type(8)));
typedef float f32x4 __attribute__((ext_vector_type(4)));

__device__ __forceinline__ unsigned short f2bf(float f) {
    unsigned u = __builtin_bit_cast(unsigned, f);
    unsigned r = u + 0x7fffu + ((u >> 16) & 1u);
    return (unsigned short)(r >> 16);
}

// out = (hv + gelu_rescaled(x)) / sqrt(2), tanh-approx gelu.
__device__ __forceinline__ float gelu_res(float x, float hv) {
    float x2 = x * x;
    float z = x * fmaf(-0.1029432196f, x2, -2.3025850930f);
    float e = __builtin_amdgcn_exp2f(z);
    float r = __builtin_amdgcn_rcpf(1.f + e);
    return fmaf(x * r, 1.2111740f, hv * 0.70710678f);
}

// ---------------------------------------------------------------------------
// Fused kernel 1:
//   blocks [0,12):    h1 per-64-row-tile column sums -> part1
//   blocks [12,316):  W1n/W1e transpose-convert -> WT bf16 (64k x 32e tiles)
//   blocks [316, +9216): h2 update (zero-LDS MFMA) + per-tile column sums
// ---------------------------------------------------------------------------
__global__ __launch_bounds__(256) void k_h2pre(
    const float* __restrict__ h2, const float* __restrict__ W2,
    const float* __restrict__ b2, const float* __restrict__ h1,
    const float* __restrict__ W1n, const float* __restrict__ W1e,
    float* __restrict__ out2, float* __restrict__ part2,
    float* __restrict__ part1, unsigned short* __restrict__ WT) {
    __shared__ union SM {
        float red[2][16][68];    // col-sum scratch (h2 path)   8704 B
        float tile2[64][33];     // W transpose tile (prefix)   8448 B
    } sm;

    int b = blockIdx.x;
    const int t = threadIdx.x;

    if (b < 12) {  // ---- h1 per-64-row-tile column sums ----
        float s = 0.f;
        #pragma unroll 8
        for (int r = 0; r < 64; ++r) s += h1[(size_t)(b * 64 + r) * 256 + t];
        part1[b * 256 + t] = s;
        return;
    }
    if (b < 316) {  // ---- W transpose-convert, 64(k) x 32(e) tiles ----
        int idx = b - 12;              // 0..303
        int mtx = idx / 152;
        int r2  = idx % 152;
        int k0 = (r2 >> 3) * 64, e0 = (r2 & 7) * 32;
        const float* W = mtx ? W1e : W1n;
        #pragma unroll
        for (int i = 0; i < 8; ++i) {
            int j = i * 256 + t;
            int kr = j >> 5, ec = j & 31;
            sm.tile2[kr][ec] = W[(size_t)(k0 + kr) * 256 + e0 + ec];
        }
        __syncthreads();
        int er = t >> 3, k8 = (t & 7) * 8;
        short8 o;
        #pragma unroll
        for (int j = 0; j < 8; ++j) o[j] = (short)f2bf(sm.tile2[k8 + j][er]);
        *reinterpret_cast<short8*>(
            &WT[((size_t)mtx * 256 + e0 + er) * 1216 + k0 + k8]) = o;
        return;
    }

    // ---- h2 update ----
    b -= 316;
    const int ct = b % 12;
    const int n  = b / 12;
    const int m0 = ct * 64;

    const int rs = (n < 128) ? 0 : ((n < 448) ? 1 : 2);
    const int cs = (ct < 2) ? 0 : ((ct < 7) ? 1 : 2);
    int p;
    if (rs == 0)      p = (cs == 0) ? 0 : 1;
    else if (rs == 1) p = (cs == 0) ? 1 : ((cs == 1) ? 2 : 3);
    else              p = (cs == 0) ? 1 : ((cs == 1) ? 3 : 2);

    const float* src = h2 + ((size_t)n * 768 + m0) * 64;
    const int lane = t & 63;
    const int wv = t >> 6;
    const int wm = wv >> 1, we = wv & 1;
    const int lr = lane & 15, lk = lane >> 4;

    // --- direct A fragment loads (f32, 8 x dwordx4, fully independent) ---
    const float* arow = src + (wm * 32 + lr) * 64 + lk * 8;
    float4 af[2][2][2];   // [fm][kh][half]
    #pragma unroll
    for (int fm = 0; fm < 2; ++fm)
        #pragma unroll
        for (int kh = 0; kh < 2; ++kh) {
            const float* pp = arow + fm * 1024 + kh * 32;
            af[fm][kh][0] = *reinterpret_cast<const float4*>(pp);
            af[fm][kh][1] = *reinterpret_cast<const float4*>(pp + 4);
        }

    // --- column partial sums into LDS (we==0 waves; 2-way banked = free) ---
    if (we == 0) {
        #pragma unroll
        for (int kh = 0; kh < 2; ++kh) {
            float4 s0, s1;
            s0.x = af[0][kh][0].x + af[1][kh][0].x;
            s0.y = af[0][kh][0].y + af[1][kh][0].y;
            s0.z = af[0][kh][0].z + af[1][kh][0].z;
            s0.w = af[0][kh][0].w + af[1][kh][0].w;
            s1.x = af[0][kh][1].x + af[1][kh][1].x;
            s1.y = af[0][kh][1].y + af[1][kh][1].y;
            s1.z = af[0][kh][1].z + af[1][kh][1].z;
            s1.w = af[0][kh][1].w + af[1][kh][1].w;
            *reinterpret_cast<float4*>(&sm.red[wm][lr][kh * 32 + lk * 8]) = s0;
            *reinterpret_cast<float4*>(&sm.red[wm][lr][kh * 32 + lk * 8 + 4]) = s1;
        }
    }

    // --- convert A to bf16 fragments ---
    short8 aF[2][2];
    #pragma unroll
    for (int fm = 0; fm < 2; ++fm)
        #pragma unroll
        for (int kh = 0; kh < 2; ++kh) {
            short8 o;
            o[0] = (short)f2bf(af[fm][kh][0].x);
            o[1] = (short)f2bf(af[fm][kh][0].y);
            o[2] = (short)f2bf(af[fm][kh][0].z);
            o[3] = (short)f2bf(af[fm][kh][0].w);
            o[4] = (short)f2bf(af[fm][kh][1].x);
            o[5] = (short)f2bf(af[fm][kh][1].y);
            o[6] = (short)f2bf(af[fm][kh][1].z);
            o[7] = (short)f2bf(af[fm][kh][1].w);
            aF[fm][kh] = o;
        }

    // --- B fragments direct from W2 (scalar f32 columns, L1/L2-hot) ---
    const float* wp = W2 + p * 4096 + we * 32 + lr;
    short8 bF[2][2];   // [fe][kh]
    #pragma unroll
    for (int fe = 0; fe < 2; ++fe)
        #pragma unroll
        for (int kh = 0; kh < 2; ++kh) {
            const float* q = wp + fe * 16 + (kh * 32 + lk * 8) * 64;
            short8 o;
            #pragma unroll
            for (int j = 0; j < 8; ++j) o[j] = (short)f2bf(q[j * 64]);
            bF[fe][kh] = o;
        }

    // --- MFMA ---
    f32x4 acc[2][2] = {};
    #pragma unroll
    for (int kh = 0; kh < 2; ++kh)
        #pragma unroll
        for (int fm = 0; fm < 2; ++fm)
            #pragma unroll
            for (int fe = 0; fe < 2; ++fe)
                acc[fm][fe] = __builtin_amdgcn_mfma_f32_16x16x32_bf16(
                    aF[fm][kh], bF[fe][kh], acc[fm][fe], 0, 0, 0);

    __syncthreads();

    // --- finalize per-tile column sums ---
    if (t < 64) {
        float s = 0.f;
        #pragma unroll
        for (int r = 0; r < 16; ++r) s += sm.red[0][r][t] + sm.red[1][r][t];
        part2[((size_t)n * 12 + ct) * 64 + t] = s;
    }

    // --- epilogue: bias + gelu + residual (re-read is L1/L2-hot) ---
    float* dst = out2 + ((size_t)n * 768 + m0) * 64;
    #pragma unroll
    for (int fm = 0; fm < 2; ++fm) {
        #pragma unroll
        for (int fe = 0; fe < 2; ++fe) {
            int e = we * 32 + fe * 16 + lr;
            float bias = b2[p * 64 + e];
            #pragma unroll
            for (int r = 0; r < 4; ++r) {
                int m = wm * 32 + fm * 16 + lk * 4 + r;
                float hv = src[m * 64 + e];
                float o = gelu_res(acc[fm][fe][r] + bias, hv);
                __builtin_nontemporal_store(o, dst + m * 64 + e);
            }
        }
    }
}

// ---------------------------------------------------------------------------
// Fused kernel 2: build feats rows (16) in LDS, then GEMM vs WT + epilogue.
// grid (48, 2), block 256 (4 waves; each wave 32 output cols).
// ---------------------------------------------------------------------------
__global__ __launch_bounds__(256) void k_h1f(
    const float* __restrict__ h1, const unsigned short* __restrict__ WT,
    const float* __restrict__ part2, const float* __restrict__ part1,
    const float* __restrict__ b1n, const float* __restrict__ b1e,
    float* __restrict__ out1) {
    __shared__ unsigned short FL[16][1224];

    const int n0 = blockIdx.x * 16;
    const int half = blockIdx.y;
    const int t = threadIdx.x;
    const bool dn = (n0 >= 448);
    const bool nucl = (n0 < 128);

    // phase 1: h1 slice (cols 0..255)
    #pragma unroll
    for (int i = 0; i < 16; ++i) {
        int idx = i * 256 + t;
        int r = idx >> 8, c = idx & 255;
        FL[r][c] = f2bf(h1[(size_t)(n0 + r) * 256 + c]);
    }
    // phase 2: h2_mean (cols 256..447)
    #pragma unroll
    for (int i = 0; i < 12; ++i) {
        int idx = i * 256 + t;
        int r = idx / 192, c = idx % 192;
        int sec = c >> 6, d = c & 63;
        int s2 = (dn && sec >= 1) ? (3 - sec) : sec;
        const float* pr = part2 + (size_t)(n0 + r) * 768;
        float s;
        if (s2 == 0) {
            s = (pr[d] + pr[64 + d]) * (1.f / 128.f);
        } else {
            int q0 = (s2 == 1) ? 2 : 7;
            s = 0.f;
            #pragma unroll
            for (int q = 0; q < 5; ++q) s += pr[(q0 + q) * 64 + d];
            s *= (1.f / 320.f);
        }
        FL[r][256 + c] = f2bf(s);
    }
    // phase 3: h1_mean (cols 448..1215), shared across the 16 rows
    #pragma unroll
    for (int i = 0; i < 3; ++i) {
        int j = i * 256 + t;
        int sec = j >> 8, e2 = j & 255;
        int s2 = (dn && sec >= 1) ? (3 - sec) : sec;
        float s;
        if (s2 == 0) {
            s = (part1[e2] + part1[256 + e2]) * (1.f / 128.f);
        } else {
            int q0 = (s2 == 1) ? 2 : 7;
            s = 0.f;
            #pragma unroll
            for (int q = 0; q < 5; ++q) s += part1[(q0 + q) * 256 + e2];
            s *= (1.f / 320.f);
        }
        unsigned short bv = f2bf(s);
        #pragma unroll
        for (int r = 0; r < 16; ++r) FL[r][448 + j] = bv;
    }
    __syncthreads();

    const int w = t >> 6, lane = t & 63;
    const int lr = lane & 15, lk = lane >> 4;
    const int e0 = half * 128 + w * 32;
    const unsigned short* BT = WT + (nucl ? 0 : (size_t)256 * 1216);
    const unsigned short* br0 = BT + (size_t)(e0 + lr) * 1216 + lk * 8;
    const unsigned short* br1 = br0 + (size_t)16 * 1216;
    const unsigned short* ar = &FL[lr][lk * 8];

    f32x4 acc0 = {}, acc1 = {};
    #pragma unroll 2
    for (int k = 0; k < 1216; k += 32) {
        short8 aF = *reinterpret_cast<const short8*>(ar + k);
        short8 b0 = *reinterpret_cast<const short8*>(br0 + k);
        short8 b1 = *reinterpret_cast<const short8*>(br1 + k);
        acc0 = __builtin_amdgcn_mfma_f32_16x16x32_bf16(aF, b0, acc0, 0, 0, 0);
        acc1 = __builtin_amdgcn_mfma_f32_16x16x32_bf16(aF, b1, acc1, 0, 0, 0);
    }

    const float* bb = nucl ? b1n : b1e;
    #pragma unroll
    for (int j = 0; j < 2; ++j) {
        const f32x4 a = j ? acc1 : acc0;
        int e = e0 + j * 16 + lr;
        float bias = bb[e];
        #pragma unroll
        for (int r = 0; r < 4; ++r) {
            int m = n0 + lk * 4 + r;
            float hv = h1[(size_t)m * 256 + e];
            out1[(size_t)m * 256 + e] = gelu_res(a[r] + bias, hv);
        }
    }
}

// ---------------------------------------------------------------------------
extern "C" void kernel_launch(void* const* d_in, const int* in_sizes, int n_in,
                              void* d_out, int out_size, void* d_ws, size_t ws_size,
                              hipStream_t stream) {
    const float* h1  = (const float*)d_in[0];
    const float* h2  = (const float*)d_in[1];
    const float* W1n = (const float*)d_in[2];
    const float* b1n = (const float*)d_in[3];
    const float* W1e = (const float*)d_in[4];
    const float* b1e = (const float*)d_in[5];
    const float* W2  = (const float*)d_in[6];
    const float* b2  = (const float*)d_in[7];

    float* out1 = (float*)d_out;             // h1_out: 768*256
    float* out2 = out1 + H1OUT_ELEMS;        // h2_out: 768*768*64

    float* part2 = (float*)d_ws;                                  // 768*12*64 f32
    float* part1 = part2 + 768 * 12 * 64;                         // 12*256 f32
    unsigned short* WT = (unsigned short*)(part1 + 12 * 256);     // 2*256*1216 bf16

    k_h2pre<<<dim3(316 + 12 * 768), 256, 0, stream>>>(
        h2, W2, b2, h1, W1n, W1e, out2, part2, part1, WT);
    k_h1f<<<dim3(48, 2), 256, 0, stream>>>(h1, WT, part2, part1, b1n, b1e, out1);
}